// Round 6
// baseline (185.441 us; speedup 1.0000x reference)
//
#include <hip/hip_runtime.h>

#define BB 32
#define CC 64
#define WW 32
#define HHT 32
#define NH 4
#define DHD 16
#define NN 1024   // W*H
#define LOG2E 1.4426950408889634f

typedef __attribute__((ext_vector_type(8))) short bf16x8;
typedef __attribute__((ext_vector_type(4))) float f32x4;

// ---------------- helpers ----------------
__device__ __forceinline__ float wave_sum(float v) {
#pragma unroll
  for (int off = 32; off > 0; off >>= 1) v += __shfl_down(v, off, 64);
  return v;
}
__device__ __forceinline__ float wave_max(float v) {
#pragma unroll
  for (int off = 32; off > 0; off >>= 1) v = fmaxf(v, __shfl_down(v, off, 64));
  return v;
}
__device__ __forceinline__ unsigned bf16pair(float lo, float hi) {
  unsigned a = __float_as_uint(lo), b = __float_as_uint(hi);
  a += 0x7FFFu + ((a >> 16) & 1u);
  b += 0x7FFFu + ((b >> 16) & 1u);
  return (a >> 16) | (b & 0xFFFF0000u);
}
__device__ __forceinline__ short bf16s(float f) {
  unsigned a = __float_as_uint(f);
  a += 0x7FFFu + ((a >> 16) & 1u);
  return (short)(a >> 16);
}

// ---------------- prep: pack weights to bf16 (A-frag layout), biases, zero LN ----
// Wb[row][c] bf16, row = (mat*4+h)*16+dd  (mat0=k scaled by log2e, 1=q, 2=v), c=0..63
__global__ __launch_bounds__(256) void prep_kernel(
    const float* __restrict__ Wq, const float* __restrict__ bq,
    const float* __restrict__ Wk, const float* __restrict__ bk,
    const float* __restrict__ Wv, const float* __restrict__ bv,
    short* __restrict__ Wb, float* __restrict__ bb, float* __restrict__ lnzero)
{
  const int tid = threadIdx.x;
  for (int idx = tid; idx < 192*32; idx += 256) {
    const int row = idx >> 5, p = idx & 31;
    const int m = row >> 4, dd = row & 15, mat = m >> 2, h = m & 3;
    const float* src = (mat == 0 ? Wk : (mat == 1 ? Wq : Wv)) + (h*16 + dd)*CC + 2*p;
    const float sc = (mat == 0) ? LOG2E : 1.f;
    reinterpret_cast<unsigned*>(Wb)[row*32 + p] = bf16pair(src[0]*sc, src[1]*sc);
  }
  if (tid < 192) {
    const int m = tid >> 4, dd = tid & 15, mat = m >> 2, h = m & 3;
    const float* bs = (mat == 0 ? bk : (mat == 1 ? bq : bv));
    bb[tid] = bs[h*16 + dd] * ((mat == 0) ? LOG2E : 1.f);
  }
  if (tid < 64) lnzero[tid] = 0.f;
}

// ---------------- MFMA QKV v3: no LDS weights, no barriers, coalesced KQ writes --
// KQ: [bh][n][32] bf16 (0..15 = k*log2e, 16..31 = q);  Vb: [bh][16 d][1024 n] bf16
__global__ __launch_bounds__(256) void qkv_kernel(
    const float* __restrict__ x, const short* __restrict__ Wb,
    const float* __restrict__ bb, short* __restrict__ KQ, short* __restrict__ Vb)
{
  __shared__ short KQt[4*16*36];   // per-wave staging tile, 36-short row stride
  const int tid = threadIdx.x;
  const int wid = tid >> 6, lane = tid & 63, Q = lane >> 4, il = lane & 15;
  const int b = blockIdx.y;
  const int nbase = blockIdx.x*64 + wid*16;
  const int n = nbase + il;
  const float* xb = x + (size_t)b * CC * NN;
  short* tw = KQt + wid*576;

  // B-frags from x (global, coalesced 64B per quad-row)
  union { bf16x8 s; unsigned u[4]; } bfr[2];
#pragma unroll
  for (int half = 0; half < 2; ++half) {
#pragma unroll
    for (int p = 0; p < 4; ++p) {
      const int c0 = 32*half + 8*Q + 2*p;
      const float f0 = xb[(size_t)c0*NN + n];
      const float f1 = xb[(size_t)(c0+1)*NN + n];
      bfr[half].u[p] = bf16pair(f0, f1);
    }
  }

  const f32x4 zero4 = {0.f, 0.f, 0.f, 0.f};
#pragma unroll
  for (int h = 0; h < NH; ++h) {
    const short* wk_ = Wb + ((h     )*16 + il)*64;
    const short* wq_ = Wb + ((4 + h)*16 + il)*64;
    const short* wv_ = Wb + ((8 + h)*16 + il)*64;
    f32x4 ak = __builtin_amdgcn_mfma_f32_16x16x32_bf16(
        *reinterpret_cast<const bf16x8*>(wk_ + 8*Q), bfr[0].s, zero4, 0, 0, 0);
    ak = __builtin_amdgcn_mfma_f32_16x16x32_bf16(
        *reinterpret_cast<const bf16x8*>(wk_ + 32 + 8*Q), bfr[1].s, ak, 0, 0, 0);
    f32x4 aq = __builtin_amdgcn_mfma_f32_16x16x32_bf16(
        *reinterpret_cast<const bf16x8*>(wq_ + 8*Q), bfr[0].s, zero4, 0, 0, 0);
    aq = __builtin_amdgcn_mfma_f32_16x16x32_bf16(
        *reinterpret_cast<const bf16x8*>(wq_ + 32 + 8*Q), bfr[1].s, aq, 0, 0, 0);
    f32x4 av = __builtin_amdgcn_mfma_f32_16x16x32_bf16(
        *reinterpret_cast<const bf16x8*>(wv_ + 8*Q), bfr[0].s, zero4, 0, 0, 0);
    av = __builtin_amdgcn_mfma_f32_16x16x32_bf16(
        *reinterpret_cast<const bf16x8*>(wv_ + 32 + 8*Q), bfr[1].s, av, 0, 0, 0);

    const float4 bk4 = *reinterpret_cast<const float4*>(bb + (h     )*16 + 4*Q);
    const float4 bq4 = *reinterpret_cast<const float4*>(bb + (4 + h)*16 + 4*Q);
    const float4 bv4 = *reinterpret_cast<const float4*>(bb + (8 + h)*16 + 4*Q);

    // stage k/q into per-wave LDS tile: row n=il, shorts d (k) / 16+d (q)
    uint2 ku, qu;
    ku.x = bf16pair(ak[0]+bk4.x, ak[1]+bk4.y); ku.y = bf16pair(ak[2]+bk4.z, ak[3]+bk4.w);
    qu.x = bf16pair(aq[0]+bq4.x, aq[1]+bq4.y); qu.y = bf16pair(aq[2]+bq4.z, aq[3]+bq4.w);
    *reinterpret_cast<uint2*>(&tw[il*36      + 4*Q]) = ku;
    *reinterpret_cast<uint2*>(&tw[il*36 + 16 + 4*Q]) = qu;

    // v: direct (32B segments per d-row)
    short* vb = Vb + ((size_t)(b*NH + h)*16 + 4*Q)*NN + n;
    vb[0]            = bf16s(av[0]+bv4.x);
    vb[(size_t)NN]   = bf16s(av[1]+bv4.y);
    vb[2*(size_t)NN] = bf16s(av[2]+bv4.z);
    vb[3*(size_t)NN] = bf16s(av[3]+bv4.w);

    // readback (same wave, lgkmcnt-ordered) & coalesced global store
    const int n2 = lane >> 2, cch = lane & 3;
    const uint2 lo = *reinterpret_cast<const uint2*>(&tw[n2*36      + cch*4]);
    const uint2 hi = *reinterpret_cast<const uint2*>(&tw[n2*36 + 16 + cch*4]);
    short* gbase = KQ + ((size_t)(b*NH + h)*NN + nbase + n2)*32;
    *reinterpret_cast<uint2*>(gbase      + cch*4) = lo;
    *reinterpret_cast<uint2*>(gbase + 16 + cch*4) = hi;
  }
}

// ---------------- MFMA flash attention v3: 32 i/wave, 1024 blocks ----------------
__global__ __launch_bounds__(256) void flash_kernel(
    const short* __restrict__ KQ, const short* __restrict__ Vb,
    const float* __restrict__ rel_h, const float* __restrict__ rel_w,
    float* __restrict__ attnout, float* __restrict__ lnsum, float* __restrict__ lnsum2)
{
  const int tid = threadIdx.x;
  const int wid = tid >> 6, lane = tid & 63;
  const int Q = lane >> 4, il = lane & 15;
  const int bh = blockIdx.x;               // bh-major: same bh lands on same XCD
  const int h = bh & 3, b = bh >> 2;
  const int ibase = blockIdx.y * 128 + wid * 32;

  // B-frags: a_i = [q(:,i) ; pos(:,i)*log2e], k-slot = 8Q + t, col i = ibase+16g2+il
  bf16x8 bfrag[2];
#pragma unroll
  for (int g2 = 0; g2 < 2; ++g2) {
    const int i = ibase + g2*16 + il;
    if (Q < 2) {
      bfrag[g2] = *reinterpret_cast<const bf16x8*>(KQ + ((size_t)bh*NN + i)*32 + 16 + 8*Q);
    } else {
      const int wrow = i >> 5, hcol = i & 31;
      union { bf16x8 s; unsigned u[4]; } t;
#pragma unroll
      for (int p = 0; p < 4; ++p) {
        const int d0 = 8*(Q-2) + 2*p;
        const float f0 = LOG2E*(rel_h[(h*DHD + d0)*HHT + hcol] + rel_w[(h*DHD + d0)*WW + wrow]);
        const float f1 = LOG2E*(rel_h[(h*DHD + d0+1)*HHT + hcol] + rel_w[(h*DHD + d0+1)*WW + wrow]);
        t.u[p] = bf16pair(f0, f1);
      }
      bfrag[g2] = t.s;
    }
  }

  const short* KQb = KQ + (size_t)bh*NN*32;
  const short* Vbb = Vb + ((size_t)bh*16 + il)*NN;   // il = d for PV B-operand
  const f32x4 zero4 = {0.f, 0.f, 0.f, 0.f};
  f32x4 acc[2] = {zero4, zero4};
  float lp[2] = {0.f, 0.f};

  // prologue: load tile jt=0
  bf16x8 agc[4]; uint2 vloc[2], vhic[2];
#pragma unroll
  for (int g = 0; g < 4; ++g)
    agc[g] = *reinterpret_cast<const bf16x8*>(KQb + (size_t)(16*g + il)*32 + 8*Q);
#pragma unroll
  for (int hh = 0; hh < 2; ++hh) {
    const short* vp = Vbb + 32*hh + 4*Q;
    vloc[hh] = *reinterpret_cast<const uint2*>(vp);
    vhic[hh] = *reinterpret_cast<const uint2*>(vp + 16);
  }

  for (int jt = 0; jt < NN; jt += 64) {
    // prefetch next tile (wraps harmlessly on last iter)
    const int jn = (jt + 64) & (NN - 1);
    bf16x8 agn[4]; uint2 vlon[2], vhin[2];
#pragma unroll
    for (int g = 0; g < 4; ++g)
      agn[g] = *reinterpret_cast<const bf16x8*>(KQb + (size_t)(jn + 16*g + il)*32 + 8*Q);
#pragma unroll
    for (int hh = 0; hh < 2; ++hh) {
      const short* vp = Vbb + jn + 32*hh + 4*Q;
      vlon[hh] = *reinterpret_cast<const uint2*>(vp);
      vhin[hh] = *reinterpret_cast<const uint2*>(vp + 16);
    }

    union { bf16x8 s; unsigned u[4]; } bv0, bv1;
    bv0.u[0] = vloc[0].x; bv0.u[1] = vloc[0].y; bv0.u[2] = vhic[0].x; bv0.u[3] = vhic[0].y;
    bv1.u[0] = vloc[1].x; bv1.u[1] = vloc[1].y; bv1.u[2] = vhic[1].x; bv1.u[3] = vhic[1].y;

#pragma unroll
    for (int g2 = 0; g2 < 2; ++g2) {
      float p[4][4];
      unsigned pk[4][2];
#pragma unroll
      for (int g = 0; g < 4; ++g) {
        const f32x4 s = __builtin_amdgcn_mfma_f32_16x16x32_bf16(agc[g], bfrag[g2], zero4, 0, 0, 0);
#pragma unroll
        for (int r = 0; r < 4; ++r) { p[g][r] = __builtin_amdgcn_exp2f(s[r]); lp[g2] += p[g][r]; }
        pk[g][0] = bf16pair(p[g][0], p[g][1]);
        pk[g][1] = bf16pair(p[g][2], p[g][3]);
      }
#pragma unroll
      for (int hh = 0; hh < 2; ++hh) {
        union { bf16x8 s; unsigned u[4]; } ap;
        ap.u[0] = pk[2*hh][0];   ap.u[1] = pk[2*hh][1];
        ap.u[2] = pk[2*hh+1][0]; ap.u[3] = pk[2*hh+1][1];
        acc[g2] = __builtin_amdgcn_mfma_f32_16x16x32_bf16(ap.s, hh ? bv1.s : bv0.s, acc[g2], 0, 0, 0);
      }
    }
#pragma unroll
    for (int g = 0; g < 4; ++g) agc[g] = agn[g];
#pragma unroll
    for (int hh = 0; hh < 2; ++hh) { vloc[hh] = vlon[hh]; vhic[hh] = vhin[hh]; }
  }

  float s1 = 0.f, s2 = 0.f;
#pragma unroll
  for (int g2 = 0; g2 < 2; ++g2) {
    float l = lp[g2];
    l += __shfl_xor(l, 16, 64);
    l += __shfl_xor(l, 32, 64);
#pragma unroll
    for (int r = 0; r < 4; ++r) {
      const float li = __shfl(l, 4*Q + r, 64);
      const float v = acc[g2][r] / li;
      const int ig = ibase + g2*16 + 4*Q + r;
      attnout[((size_t)b*CC + h*DHD + il)*NN + ig] = v;
      s1 += v; s2 += v*v;
    }
  }
  s1 = wave_sum(s1); s2 = wave_sum(s2);
  __shared__ float r1[4], r2[4];
  if (lane == 0) { r1[wid] = s1; r2[wid] = s2; }
  __syncthreads();
  if (tid == 0) {
    atomicAdd(&lnsum[b],  r1[0]+r1[1]+r1[2]+r1[3]);
    atomicAdd(&lnsum2[b], r2[0]+r2[1]+r2[2]+r2[3]);
  }
}

// ---------------- CBAM channel stats ----------------
__global__ __launch_bounds__(256) void cbamstats_kernel(
    const float* __restrict__ x, float* __restrict__ avg, float* __restrict__ mx)
{
  const int bc = blockIdx.x, tid = threadIdx.x;
  const float* p = x + (size_t)bc*NN;
  float s = 0.f, m = -3.0e38f;
  for (int u = tid; u < NN; u += 256) { const float v = p[u]; s += v; m = fmaxf(m, v); }
  s = wave_sum(s); m = wave_max(m);
  __shared__ float rs[4], rm[4];
  const int wid = tid >> 6, lane = tid & 63;
  if (lane == 0) { rs[wid] = s; rm[wid] = m; }
  __syncthreads();
  if (tid == 0) {
    avg[bc] = (rs[0]+rs[1]+rs[2]+rs[3]) * (1.f/NN);
    mx[bc]  = fmaxf(fmaxf(rm[0], rm[1]), fmaxf(rm[2], rm[3]));
  }
}

// ---------------- channel-attention MLP (recomputed per block) + spatial feats ----
__global__ __launch_bounds__(256) void mlpfeat_kernel(
    const float* __restrict__ x, const float* __restrict__ avg, const float* __restrict__ mxv,
    const float* __restrict__ w1, const float* __restrict__ b1,
    const float* __restrict__ w2, const float* __restrict__ b2,
    float* __restrict__ chv, float* __restrict__ feat)
{
  const int b = blockIdx.y, qq = blockIdx.x, tid = threadIdx.x;
  __shared__ float sa[CC], sm[CC], sch[CC];
  __shared__ float ps[4][64], pm[4][64];
  if (tid < CC) { sa[tid] = avg[b*CC + tid]; sm[tid] = mxv[b*CC + tid]; }
  __syncthreads();
  if (tid < CC) {
    float s = 2.f * b2[tid];
#pragma unroll
    for (int o = 0; o < 4; ++o) {
      float ha = b1[o], hm = b1[o];
#pragma unroll
      for (int k = 0; k < CC; ++k) { ha += w1[o*CC + k]*sa[k]; hm += w1[o*CC + k]*sm[k]; }
      s += w2[tid*4 + o] * (fmaxf(ha, 0.f) + fmaxf(hm, 0.f));
    }
    const float c = 1.f/(1.f + __expf(-s));
    sch[tid] = c;
    if (qq == 0) chv[b*CC + tid] = c;
  }
  __syncthreads();
  const int nl = tid & 63, cg = tid >> 6;
  const int n = qq*64 + nl;
  float s = 0.f, m = -3.0e38f;
#pragma unroll
  for (int c = cg*16; c < cg*16 + 16; ++c) {
    const float v = sch[c] * x[((size_t)b*CC + c)*NN + n];
    s += v; m = fmaxf(m, v);
  }
  ps[cg][nl] = s; pm[cg][nl] = m;
  __syncthreads();
  if (cg == 0) {
    const float S = ps[0][nl]+ps[1][nl]+ps[2][nl]+ps[3][nl];
    const float M = fmaxf(fmaxf(pm[0][nl], pm[1][nl]), fmaxf(pm[2][nl], pm[3][nl]));
    feat[(size_t)b*2*NN + n]      = S * (1.f/CC);
    feat[(size_t)b*2*NN + NN + n] = M;
  }
}

// ---------------- 7x7 conv + LN + fused final combine (c-split for parallelism) ----
__global__ __launch_bounds__(256) void final_kernel(
    const float* __restrict__ x, const float* __restrict__ attn,
    const float* __restrict__ ln_g, const float* __restrict__ ln_b,
    const float* __restrict__ feat, const float* __restrict__ ch,
    const float* __restrict__ lnsum, const float* __restrict__ lnsum2,
    const float* __restrict__ sa_w, const float* __restrict__ sa_b,
    float* __restrict__ out)
{
  const int b = blockIdx.y;
  const int c0 = blockIdx.z * 16;
  const int n = blockIdx.x*256 + threadIdx.x;
  const int w = n >> 5, hh = n & 31;
  __shared__ float sch[CC];
  __shared__ float swt[98];
  if (threadIdx.x < CC) sch[threadIdx.x] = ch[b*CC + threadIdx.x];
  if (threadIdx.x < 98) swt[threadIdx.x] = sa_w[threadIdx.x];
  __syncthreads();

  float s = sa_b[0];
#pragma unroll
  for (int ci = 0; ci < 2; ++ci)
#pragma unroll
    for (int kh = 0; kh < 7; ++kh) {
      const int wy = w + kh - 3;
      if (wy < 0 || wy >= WW) continue;
#pragma unroll
      for (int kw = 0; kw < 7; ++kw) {
        const int hx = hh + kw - 3;
        if (hx < 0 || hx >= HHT) continue;
        s += feat[((size_t)(b*2) + ci)*NN + wy*HHT + hx] * swt[ci*49 + kh*7 + kw];
      }
    }
  const float sg = 1.f/(1.f + __expf(-s));
  const float inv = 1.f/(CC*NN);
  const float m = lnsum[b]*inv;
  const float var = lnsum2[b]*inv - m*m;
  const float r = rsqrtf(var + 1e-5f);
#pragma unroll
  for (int c = c0; c < c0 + 16; ++c) {
    const size_t idx = ((size_t)b*CC + c)*NN + n;
    const float xa = x[idx];
    const float ln = (attn[idx] - m) * r * ln_g[c*NN + n] + ln_b[c*NN + n];
    out[idx] = ln + 2.f*xa + sg * sch[c] * xa;
  }
}

extern "C" void kernel_launch(void* const* d_in, const int* in_sizes, int n_in,
                              void* d_out, int out_size, void* d_ws, size_t ws_size,
                              hipStream_t stream)
{
  const float* x     = (const float*)d_in[0];
  const float* Wq    = (const float*)d_in[1];
  const float* bq    = (const float*)d_in[2];
  const float* Wk    = (const float*)d_in[3];
  const float* bk    = (const float*)d_in[4];
  const float* Wv    = (const float*)d_in[5];
  const float* bv    = (const float*)d_in[6];
  const float* rel_h = (const float*)d_in[7];
  const float* rel_w = (const float*)d_in[8];
  const float* ln_g  = (const float*)d_in[9];
  const float* ln_b  = (const float*)d_in[10];
  const float* cw1   = (const float*)d_in[11];
  const float* cb1   = (const float*)d_in[12];
  const float* cw2   = (const float*)d_in[13];
  const float* cb2   = (const float*)d_in[14];
  const float* saw   = (const float*)d_in[15];
  const float* sab   = (const float*)d_in[16];
  float* out = (float*)d_out;

  short* KQ = (short*)d_ws;                    // 128*1024*32 shorts = 8 MB
  short* Vb = KQ + (size_t)128*1024*32;        // 128*16*1024 shorts = 4 MB
  float* fs = (float*)(Vb + (size_t)128*16*1024);
  float* lnsum  = fs;             // 32 (+32 lnsum2, zeroed in prep)
  float* lnsum2 = fs + 32;
  float* avg    = fs + 64;        // 2048
  float* mxv    = avg + 2048;     // 2048
  float* chv    = mxv + 2048;     // 2048
  float* feat   = chv + 2048;     // 65536
  short* Wb     = (short*)(feat + 65536);  // 192*64 = 12288 shorts
  float* bb     = (float*)(Wb + 12288);    // 192 floats
  float* attn   = out;            // attention output lives in d_out (in-place final)

  prep_kernel<<<1, 256, 0, stream>>>(Wq, bq, Wk, bk, Wv, bv, Wb, bb, lnsum);
  qkv_kernel<<<dim3(16, BB), 256, 0, stream>>>(x, Wb, bb, KQ, Vb);
  flash_kernel<<<dim3(BB*NH, 8), 256, 0, stream>>>(KQ, Vb, rel_h, rel_w, attn, lnsum, lnsum2);
  cbamstats_kernel<<<BB*CC, 256, 0, stream>>>(x, avg, mxv);
  mlpfeat_kernel<<<dim3(16, BB), 256, 0, stream>>>(x, avg, mxv, cw1, cb1, cw2, cb2, chv, feat);
  final_kernel<<<dim3(4, BB, 4), 256, 0, stream>>>(x, attn, ln_g, ln_b, feat, chv, lnsum, lnsum2, saw, sab, out);
}

// Round 7
// 175.227 us; speedup vs baseline: 1.0583x; 1.0583x over previous
//
#include <hip/hip_runtime.h>

#define BB 32
#define CC 64
#define WW 32
#define HHT 32
#define NH 4
#define DHD 16
#define NN 1024   // W*H
#define LOG2E 1.4426950408889634f

typedef __attribute__((ext_vector_type(8))) short bf16x8;
typedef __attribute__((ext_vector_type(4))) float f32x4;

// ---------------- helpers ----------------
__device__ __forceinline__ float wave_sum(float v) {
#pragma unroll
  for (int off = 32; off > 0; off >>= 1) v += __shfl_down(v, off, 64);
  return v;
}
__device__ __forceinline__ float wave_max(float v) {
#pragma unroll
  for (int off = 32; off > 0; off >>= 1) v = fmaxf(v, __shfl_down(v, off, 64));
  return v;
}
__device__ __forceinline__ unsigned bf16pair(float lo, float hi) {
  unsigned a = __float_as_uint(lo), b = __float_as_uint(hi);
  a += 0x7FFFu + ((a >> 16) & 1u);
  b += 0x7FFFu + ((b >> 16) & 1u);
  return (a >> 16) | (b & 0xFFFF0000u);
}
// truncating pack: hi16(f1) | hi16(f0)>>16 — one v_perm_b32
__device__ __forceinline__ unsigned bf16pair_trunc(float lo, float hi) {
  return __builtin_amdgcn_perm(__float_as_uint(hi), __float_as_uint(lo), 0x07060302u);
}
__device__ __forceinline__ short bf16s(float f) {
  unsigned a = __float_as_uint(f);
  a += 0x7FFFu + ((a >> 16) & 1u);
  return (short)(a >> 16);
}

// ---------------- MFMA QKV projection (R5 version) ----------------
// KQ: [bh][n][32] bf16, shorts 0..15 = k_d[n]*log2e, 16..31 = q_d[n]
// Vb: [bh][16 d][1024 n] bf16
__global__ __launch_bounds__(256) void qkv_kernel(
    const float* __restrict__ x,
    const float* __restrict__ Wq, const float* __restrict__ bq,
    const float* __restrict__ Wk, const float* __restrict__ bk,
    const float* __restrict__ Wv, const float* __restrict__ bv,
    short* __restrict__ KQ, short* __restrict__ Vb, float* __restrict__ lnzero)
{
  __shared__ __align__(16) short Ws[192 * 72];   // [r][k], r = m*16+dd, stride 72 shorts
  const int tid = threadIdx.x;
  const int b = blockIdx.y, nt = blockIdx.x;

  if (tid < 192) {
    const int m = tid >> 4, dd = tid & 15;
    const int mat = m >> 2, h = m & 3;
    const float* src = (mat == 0 ? Wk : (mat == 1 ? Wq : Wv)) + (h * 16 + dd) * CC;
    const float scale = (mat == 0) ? LOG2E : 1.f;
    short* dst = Ws + tid * 72;
#pragma unroll
    for (int c8 = 0; c8 < 8; ++c8) {
      const float4 f0 = *reinterpret_cast<const float4*>(src + c8 * 8);
      const float4 f1 = *reinterpret_cast<const float4*>(src + c8 * 8 + 4);
      uint4 u;
      u.x = bf16pair(f0.x*scale, f0.y*scale); u.y = bf16pair(f0.z*scale, f0.w*scale);
      u.z = bf16pair(f1.x*scale, f1.y*scale); u.w = bf16pair(f1.z*scale, f1.w*scale);
      *reinterpret_cast<uint4*>(dst + c8 * 8) = u;
    }
  }
  if (blockIdx.x == 0 && blockIdx.y == 0 && tid < 64) lnzero[tid] = 0.f;  // lnsum+lnsum2
  __syncthreads();

  const int wid = tid >> 6, lane = tid & 63, Q = lane >> 4, il = lane & 15;
  const int n = nt * 64 + wid * 16 + il;
  const float* xb = x + (size_t)b * CC * NN;

  union { bf16x8 s; unsigned u[4]; } bfr[2];
#pragma unroll
  for (int half = 0; half < 2; ++half) {
#pragma unroll
    for (int p = 0; p < 4; ++p) {
      const int c0 = 32 * half + 8 * Q + 2 * p;
      const float f0 = xb[(size_t)c0 * NN + n];
      const float f1 = xb[(size_t)(c0 + 1) * NN + n];
      bfr[half].u[p] = bf16pair(f0, f1);
    }
  }

  const f32x4 zero4 = {0.f, 0.f, 0.f, 0.f};
  f32x4 acc[12];
#pragma unroll
  for (int m = 0; m < 12; ++m) {
    const short* wr = Ws + (m * 16 + il) * 72;
    const bf16x8 a0 = *reinterpret_cast<const bf16x8*>(wr + 8 * Q);
    const bf16x8 a1 = *reinterpret_cast<const bf16x8*>(wr + 32 + 8 * Q);
    acc[m] = __builtin_amdgcn_mfma_f32_16x16x32_bf16(a0, bfr[0].s, zero4, 0, 0, 0);
    acc[m] = __builtin_amdgcn_mfma_f32_16x16x32_bf16(a1, bfr[1].s, acc[m], 0, 0, 0);
  }

#pragma unroll
  for (int m = 0; m < 12; ++m) {
    const int mat = m >> 2, h = m & 3;
    const float bsc = (mat == 0) ? LOG2E : 1.f;
    const float4 bias = *reinterpret_cast<const float4*>(
        (mat == 0 ? bk : (mat == 1 ? bq : bv)) + h * 16 + 4 * Q);
    const float v0 = acc[m][0] + bias.x*bsc, v1 = acc[m][1] + bias.y*bsc;
    const float v2 = acc[m][2] + bias.z*bsc, v3 = acc[m][3] + bias.w*bsc;
    if (mat < 2) {
      uint2 pk;
      pk.x = bf16pair(v0, v1); pk.y = bf16pair(v2, v3);
      *reinterpret_cast<uint2*>(KQ + ((size_t)(b * NH + h) * NN + n) * 32 +
                                (mat == 0 ? 0 : 16) + 4 * Q) = pk;
    } else {
      short* vb = Vb + ((size_t)(b * NH + h) * 16 + 4 * Q) * NN + n;
      vb[0]            = bf16s(v0);
      vb[(size_t)NN]   = bf16s(v1);
      vb[2*(size_t)NN] = bf16s(v2);
      vb[3*(size_t)NN] = bf16s(v3);
    }
  }
}

// ---------------- MFMA flash attention v4: 64 i/wave, 2 j-streams, perm-pack ----
__global__ __launch_bounds__(256, 2) void flash_kernel(
    const short* __restrict__ KQ, const short* __restrict__ Vb,
    const float* __restrict__ rel_h, const float* __restrict__ rel_w,
    float* __restrict__ attnout, float* __restrict__ lnsum, float* __restrict__ lnsum2)
{
  const int tid = threadIdx.x;
  const int wid = tid >> 6, lane = tid & 63;
  const int Q = lane >> 4, il = lane & 15;
  const int bh = blockIdx.x;               // bh-major: same bh lands on same XCD
  const int h = bh & 3, b = bh >> 2;
  const int ibase = blockIdx.y * 256 + wid * 64;

  // B-frags: a_i = [q(:,i) ; pos(:,i)*log2e], k-slot = 8Q + t, col i = ibase+16g2+il
  bf16x8 bfrag[4];
#pragma unroll
  for (int g2 = 0; g2 < 4; ++g2) {
    const int i = ibase + g2*16 + il;
    if (Q < 2) {
      bfrag[g2] = *reinterpret_cast<const bf16x8*>(KQ + ((size_t)bh*NN + i)*32 + 16 + 8*Q);
    } else {
      const int wrow = i >> 5, hcol = i & 31;
      union { bf16x8 s; unsigned u[4]; } t;
#pragma unroll
      for (int p = 0; p < 4; ++p) {
        const int d0 = 8*(Q-2) + 2*p;
        const float f0 = LOG2E*(rel_h[(h*DHD + d0)*HHT + hcol] + rel_w[(h*DHD + d0)*WW + wrow]);
        const float f1 = LOG2E*(rel_h[(h*DHD + d0+1)*HHT + hcol] + rel_w[(h*DHD + d0+1)*WW + wrow]);
        t.u[p] = bf16pair(f0, f1);
      }
      bfrag[g2] = t.s;
    }
  }

  const short* KQb = KQ + (size_t)bh*NN*32;
  const short* Vbb = Vb + ((size_t)bh*16 + il)*NN;   // il = d for PV B-operand
  const f32x4 zero4 = {0.f, 0.f, 0.f, 0.f};
  f32x4 accA[4] = {zero4, zero4, zero4, zero4};
  f32x4 accB[4] = {zero4, zero4, zero4, zero4};
  float lpA[4] = {0.f, 0.f, 0.f, 0.f};
  float lpB[4] = {0.f, 0.f, 0.f, 0.f};

  // prologue: load tiles j=0 (stream A) and j=512 (stream B)
  bf16x8 agA[4], agB[4]; uint2 vloA[2], vhiA[2], vloB[2], vhiB[2];
#pragma unroll
  for (int g = 0; g < 4; ++g) {
    agA[g] = *reinterpret_cast<const bf16x8*>(KQb + (size_t)(      16*g + il)*32 + 8*Q);
    agB[g] = *reinterpret_cast<const bf16x8*>(KQb + (size_t)(512 + 16*g + il)*32 + 8*Q);
  }
#pragma unroll
  for (int hh = 0; hh < 2; ++hh) {
    const short* vpA = Vbb + 32*hh + 4*Q;
    const short* vpB = Vbb + 512 + 32*hh + 4*Q;
    vloA[hh] = *reinterpret_cast<const uint2*>(vpA);
    vhiA[hh] = *reinterpret_cast<const uint2*>(vpA + 16);
    vloB[hh] = *reinterpret_cast<const uint2*>(vpB);
    vhiB[hh] = *reinterpret_cast<const uint2*>(vpB + 16);
  }

  for (int jt = 0; jt < 512; jt += 64) {
    const int jn = (jt + 64) & 511;          // wraps harmlessly on last iter
    bf16x8 agAn[4], agBn[4]; uint2 vloAn[2], vhiAn[2], vloBn[2], vhiBn[2];
#pragma unroll
    for (int g = 0; g < 4; ++g) {
      agAn[g] = *reinterpret_cast<const bf16x8*>(KQb + (size_t)(      jn + 16*g + il)*32 + 8*Q);
      agBn[g] = *reinterpret_cast<const bf16x8*>(KQb + (size_t)(512 + jn + 16*g + il)*32 + 8*Q);
    }
#pragma unroll
    for (int hh = 0; hh < 2; ++hh) {
      const short* vpA = Vbb + jn + 32*hh + 4*Q;
      const short* vpB = Vbb + 512 + jn + 32*hh + 4*Q;
      vloAn[hh] = *reinterpret_cast<const uint2*>(vpA);
      vhiAn[hh] = *reinterpret_cast<const uint2*>(vpA + 16);
      vloBn[hh] = *reinterpret_cast<const uint2*>(vpB);
      vhiBn[hh] = *reinterpret_cast<const uint2*>(vpB + 16);
    }

    union { bf16x8 s; unsigned u[4]; } bvA0, bvA1, bvB0, bvB1;
    bvA0.u[0] = vloA[0].x; bvA0.u[1] = vloA[0].y; bvA0.u[2] = vhiA[0].x; bvA0.u[3] = vhiA[0].y;
    bvA1.u[0] = vloA[1].x; bvA1.u[1] = vloA[1].y; bvA1.u[2] = vhiA[1].x; bvA1.u[3] = vhiA[1].y;
    bvB0.u[0] = vloB[0].x; bvB0.u[1] = vloB[0].y; bvB0.u[2] = vhiB[0].x; bvB0.u[3] = vhiB[0].y;
    bvB1.u[0] = vloB[1].x; bvB1.u[1] = vloB[1].y; bvB1.u[2] = vhiB[1].x; bvB1.u[3] = vhiB[1].y;

#pragma unroll
    for (int g2 = 0; g2 < 4; ++g2) {
      // ---- stream A chain ----
      {
        float p[4][4];
        unsigned pk[4][2];
#pragma unroll
        for (int g = 0; g < 4; ++g) {
          const f32x4 s = __builtin_amdgcn_mfma_f32_16x16x32_bf16(agA[g], bfrag[g2], zero4, 0, 0, 0);
#pragma unroll
          for (int r = 0; r < 4; ++r) p[g][r] = __builtin_amdgcn_exp2f(s[r]);
          lpA[g2] += (p[g][0] + p[g][1]) + (p[g][2] + p[g][3]);
          pk[g][0] = bf16pair_trunc(p[g][0], p[g][1]);
          pk[g][1] = bf16pair_trunc(p[g][2], p[g][3]);
        }
#pragma unroll
        for (int hh = 0; hh < 2; ++hh) {
          union { bf16x8 s; unsigned u[4]; } ap;
          ap.u[0] = pk[2*hh][0];   ap.u[1] = pk[2*hh][1];
          ap.u[2] = pk[2*hh+1][0]; ap.u[3] = pk[2*hh+1][1];
          accA[g2] = __builtin_amdgcn_mfma_f32_16x16x32_bf16(ap.s, hh ? bvA1.s : bvA0.s, accA[g2], 0, 0, 0);
        }
      }
      // ---- stream B chain (independent) ----
      {
        float p[4][4];
        unsigned pk[4][2];
#pragma unroll
        for (int g = 0; g < 4; ++g) {
          const f32x4 s = __builtin_amdgcn_mfma_f32_16x16x32_bf16(agB[g], bfrag[g2], zero4, 0, 0, 0);
#pragma unroll
          for (int r = 0; r < 4; ++r) p[g][r] = __builtin_amdgcn_exp2f(s[r]);
          lpB[g2] += (p[g][0] + p[g][1]) + (p[g][2] + p[g][3]);
          pk[g][0] = bf16pair_trunc(p[g][0], p[g][1]);
          pk[g][1] = bf16pair_trunc(p[g][2], p[g][3]);
        }
#pragma unroll
        for (int hh = 0; hh < 2; ++hh) {
          union { bf16x8 s; unsigned u[4]; } ap;
          ap.u[0] = pk[2*hh][0];   ap.u[1] = pk[2*hh][1];
          ap.u[2] = pk[2*hh+1][0]; ap.u[3] = pk[2*hh+1][1];
          accB[g2] = __builtin_amdgcn_mfma_f32_16x16x32_bf16(ap.s, hh ? bvB1.s : bvB0.s, accB[g2], 0, 0, 0);
        }
      }
    }
#pragma unroll
    for (int g = 0; g < 4; ++g) { agA[g] = agAn[g]; agB[g] = agBn[g]; }
#pragma unroll
    for (int hh = 0; hh < 2; ++hh) {
      vloA[hh] = vloAn[hh]; vhiA[hh] = vhiAn[hh];
      vloB[hh] = vloBn[hh]; vhiB[hh] = vhiBn[hh];
    }
  }

  float s1 = 0.f, s2 = 0.f;
#pragma unroll
  for (int g2 = 0; g2 < 4; ++g2) {
    float l = lpA[g2] + lpB[g2];
    l += __shfl_xor(l, 16, 64);
    l += __shfl_xor(l, 32, 64);
#pragma unroll
    for (int r = 0; r < 4; ++r) {
      const float li = __shfl(l, 4*Q + r, 64);
      const float v = (accA[g2][r] + accB[g2][r]) / li;
      const int ig = ibase + g2*16 + 4*Q + r;
      attnout[((size_t)b*CC + h*DHD + il)*NN + ig] = v;
      s1 += v; s2 += v*v;
    }
  }
  s1 = wave_sum(s1); s2 = wave_sum(s2);
  __shared__ float r1[4], r2[4];
  if (lane == 0) { r1[wid] = s1; r2[wid] = s2; }
  __syncthreads();
  if (tid == 0) {
    atomicAdd(&lnsum[b],  r1[0]+r1[1]+r1[2]+r1[3]);
    atomicAdd(&lnsum2[b], r2[0]+r2[1]+r2[2]+r2[3]);
  }
}

// ---------------- CBAM channel stats ----------------
__global__ __launch_bounds__(256) void cbamstats_kernel(
    const float* __restrict__ x, float* __restrict__ avg, float* __restrict__ mx)
{
  const int bc = blockIdx.x, tid = threadIdx.x;
  const float* p = x + (size_t)bc*NN;
  float s = 0.f, m = -3.0e38f;
  for (int u = tid; u < NN; u += 256) { const float v = p[u]; s += v; m = fmaxf(m, v); }
  s = wave_sum(s); m = wave_max(m);
  __shared__ float rs[4], rm[4];
  const int wid = tid >> 6, lane = tid & 63;
  if (lane == 0) { rs[wid] = s; rm[wid] = m; }
  __syncthreads();
  if (tid == 0) {
    avg[bc] = (rs[0]+rs[1]+rs[2]+rs[3]) * (1.f/NN);
    mx[bc]  = fmaxf(fmaxf(rm[0], rm[1]), fmaxf(rm[2], rm[3]));
  }
}

// ---------------- channel-attention MLP (recomputed per block) + spatial feats ----
__global__ __launch_bounds__(256) void mlpfeat_kernel(
    const float* __restrict__ x, const float* __restrict__ avg, const float* __restrict__ mxv,
    const float* __restrict__ w1, const float* __restrict__ b1,
    const float* __restrict__ w2, const float* __restrict__ b2,
    float* __restrict__ chv, float* __restrict__ feat)
{
  const int b = blockIdx.y, qq = blockIdx.x, tid = threadIdx.x;
  __shared__ float sa[CC], sm[CC], sch[CC];
  __shared__ float ps[4][64], pm[4][64];
  if (tid < CC) { sa[tid] = avg[b*CC + tid]; sm[tid] = mxv[b*CC + tid]; }
  __syncthreads();
  if (tid < CC) {
    float s = 2.f * b2[tid];
#pragma unroll
    for (int o = 0; o < 4; ++o) {
      float ha = b1[o], hm = b1[o];
#pragma unroll
      for (int k = 0; k < CC; ++k) { ha += w1[o*CC + k]*sa[k]; hm += w1[o*CC + k]*sm[k]; }
      s += w2[tid*4 + o] * (fmaxf(ha, 0.f) + fmaxf(hm, 0.f));
    }
    const float c = 1.f/(1.f + __expf(-s));
    sch[tid] = c;
    if (qq == 0) chv[b*CC + tid] = c;
  }
  __syncthreads();
  const int nl = tid & 63, cg = tid >> 6;
  const int n = qq*64 + nl;
  float s = 0.f, m = -3.0e38f;
#pragma unroll
  for (int c = cg*16; c < cg*16 + 16; ++c) {
    const float v = sch[c] * x[((size_t)b*CC + c)*NN + n];
    s += v; m = fmaxf(m, v);
  }
  ps[cg][nl] = s; pm[cg][nl] = m;
  __syncthreads();
  if (cg == 0) {
    const float S = ps[0][nl]+ps[1][nl]+ps[2][nl]+ps[3][nl];
    const float M = fmaxf(fmaxf(pm[0][nl], pm[1][nl]), fmaxf(pm[2][nl], pm[3][nl]));
    feat[(size_t)b*2*NN + n]      = S * (1.f/CC);
    feat[(size_t)b*2*NN + NN + n] = M;
  }
}

// ---------------- 7x7 conv + LN + fused final combine (c-split x8) ----------------
__global__ __launch_bounds__(256) void final_kernel(
    const float* __restrict__ x, const float* __restrict__ attn,
    const float* __restrict__ ln_g, const float* __restrict__ ln_b,
    const float* __restrict__ feat, const float* __restrict__ ch,
    const float* __restrict__ lnsum, const float* __restrict__ lnsum2,
    const float* __restrict__ sa_w, const float* __restrict__ sa_b,
    float* __restrict__ out)
{
  const int b = blockIdx.y;
  const int c0 = blockIdx.z * 8;
  const int n = blockIdx.x*256 + threadIdx.x;
  const int w = n >> 5, hh = n & 31;
  __shared__ float sch[CC];
  __shared__ float swt[98];
  if (threadIdx.x < CC) sch[threadIdx.x] = ch[b*CC + threadIdx.x];
  if (threadIdx.x < 98) swt[threadIdx.x] = sa_w[threadIdx.x];
  __syncthreads();

  float s = sa_b[0];
#pragma unroll
  for (int ci = 0; ci < 2; ++ci)
#pragma unroll
    for (int kh = 0; kh < 7; ++kh) {
      const int wy = w + kh - 3;
      if (wy < 0 || wy >= WW) continue;
#pragma unroll
      for (int kw = 0; kw < 7; ++kw) {
        const int hx = hh + kw - 3;
        if (hx < 0 || hx >= HHT) continue;
        s += feat[((size_t)(b*2) + ci)*NN + wy*HHT + hx] * swt[ci*49 + kh*7 + kw];
      }
    }
  const float sg = 1.f/(1.f + __expf(-s));
  const float inv = 1.f/(CC*NN);
  const float m = lnsum[b]*inv;
  const float var = lnsum2[b]*inv - m*m;
  const float r = rsqrtf(var + 1e-5f);
#pragma unroll
  for (int c = c0; c < c0 + 8; ++c) {
    const size_t idx = ((size_t)b*CC + c)*NN + n;
    const float xa = x[idx];
    const float ln = (attn[idx] - m) * r * ln_g[c*NN + n] + ln_b[c*NN + n];
    out[idx] = ln + 2.f*xa + sg * sch[c] * xa;
  }
}

extern "C" void kernel_launch(void* const* d_in, const int* in_sizes, int n_in,
                              void* d_out, int out_size, void* d_ws, size_t ws_size,
                              hipStream_t stream)
{
  const float* x     = (const float*)d_in[0];
  const float* Wq    = (const float*)d_in[1];
  const float* bq    = (const float*)d_in[2];
  const float* Wk    = (const float*)d_in[3];
  const float* bk    = (const float*)d_in[4];
  const float* Wv    = (const float*)d_in[5];
  const float* bv    = (const float*)d_in[6];
  const float* rel_h = (const float*)d_in[7];
  const float* rel_w = (const float*)d_in[8];
  const float* ln_g  = (const float*)d_in[9];
  const float* ln_b  = (const float*)d_in[10];
  const float* cw1   = (const float*)d_in[11];
  const float* cb1   = (const float*)d_in[12];
  const float* cw2   = (const float*)d_in[13];
  const float* cb2   = (const float*)d_in[14];
  const float* saw   = (const float*)d_in[15];
  const float* sab   = (const float*)d_in[16];
  float* out = (float*)d_out;

  short* KQ = (short*)d_ws;                    // 128*1024*32 shorts = 8 MB
  short* Vb = KQ + (size_t)128*1024*32;        // 128*16*1024 shorts = 4 MB
  float* fs = (float*)(Vb + (size_t)128*16*1024);
  float* lnsum  = fs;             // 32 (+32 lnsum2, zeroed in qkv)
  float* lnsum2 = fs + 32;
  float* avg    = fs + 64;        // 2048
  float* mxv    = avg + 2048;     // 2048
  float* chv    = mxv + 2048;     // 2048
  float* feat   = chv + 2048;     // 65536
  float* attn   = out;            // attention output lives in d_out (in-place final)

  qkv_kernel<<<dim3(16, BB), 256, 0, stream>>>(x, Wq, bq, Wk, bk, Wv, bv, KQ, Vb, lnsum);
  flash_kernel<<<dim3(BB*NH, 4), 256, 0, stream>>>(KQ, Vb, rel_h, rel_w, attn, lnsum, lnsum2);
  cbamstats_kernel<<<BB*CC, 256, 0, stream>>>(x, avg, mxv);
  mlpfeat_kernel<<<dim3(16, BB), 256, 0, stream>>>(x, avg, mxv, cw1, cb1, cw2, cb2, chv, feat);
  final_kernel<<<dim3(4, BB, 8), 256, 0, stream>>>(x, attn, ln_g, ln_b, feat, chv, lnsum, lnsum2, saw, sab, out);
}